// Round 3
// baseline (401.686 us; speedup 1.0000x reference)
//
#include <hip/hip_runtime.h>
#include <hip/hip_bf16.h>
#include <cmath>

// Problem constants (Qwen3 MoE block)
constexpr int T = 2048;   // tokens (B*S)
constexpr int H = 1024;   // hidden
constexpr int I = 768;    // intermediate
constexpr int E = 16;     // experts
constexpr int WMAX = 48;  // max M-tiles at M=128: sum ceil(n_e/128) <= 48

typedef short short8 __attribute__((ext_vector_type(8)));
typedef float f32x4  __attribute__((ext_vector_type(4)));

__device__ __forceinline__ short f2bf(float f) {
    __hip_bfloat16 h = __float2bfloat16(f);   // RNE
    return *reinterpret_cast<short*>(&h);
}

__device__ __forceinline__ short8 pack8(float4 a, float4 b) {
    short8 v = {f2bf(a.x), f2bf(a.y), f2bf(a.z), f2bf(a.w),
                f2bf(b.x), f2bf(b.y), f2bf(b.z), f2bf(b.w)};
    return v;
}

// Uniform prefix scan over cnt[] (replaces a worklist kernel).
__device__ __forceinline__ bool find_item(const int* __restrict__ cnt, int bx,
                                          int& e_o, int& t0_o, int& n_o) {
    int c = 0;
    #pragma unroll
    for (int e = 0; e < E; ++e) {
        int n = cnt[e];
        int m = (n + 127) >> 7;
        if (bx < c + m) { e_o = e; t0_o = (bx - c) << 7; n_o = n; return true; }
        c += m;
    }
    return false;
}

// ------------------------------------------------------------------
// Router (fused x->bf16 conversion): block = 8 tokens x 16 experts
// x 2 H-halves. Each thread does a half-H fp32 dot (2 KB of loads,
// halves the latency-bound depth vs one full-H dot); the (e,hf)
// thread owning q-slice [hf*128 + e*8, +8) also emits those x values
// as bf16 (already in registers).
// ------------------------------------------------------------------
__global__ __launch_bounds__(256) void router_kernel(
    const float* __restrict__ x,     // [T,H]
    const float* __restrict__ gw,    // [E,H]
    short* __restrict__ xb,          // [T,H] bf16 out
    int* __restrict__ cnt,           // [E]
    int* __restrict__ entries,       // [E,T]  value = t*2 + k
    float* __restrict__ wlist)       // [E,T]
{
    const int tid = threadIdx.x;
    const int tl = tid & 7;              // token
    const int e  = (tid >> 3) & 15;      // expert
    const int hf = tid >> 7;             // H-half
    const int t  = blockIdx.x * 8 + tl;

    const float4* xr = (const float4*)(x + (size_t)t * H);
    const float4* gr = (const float4*)(gw + (size_t)e * H);
    short* xrow = xb + (size_t)t * H;

    float s0 = 0.f, s1 = 0.f;
    const int qlo = hf * 128, qhi = qlo + 128;
    #pragma unroll 8
    for (int q = qlo; q < qhi; q += 2) {
        float4 a = xr[q],     b = gr[q];
        float4 c = xr[q + 1], d = gr[q + 1];
        s0 += a.x * b.x + a.y * b.y + a.z * b.z + a.w * b.w;
        s1 += c.x * d.x + c.y * d.y + c.z * d.z + c.w * d.w;
        if (((q >> 3) & 15) == e)
            *(short8*)(xrow + q * 4) = pack8(a, c);   // 16B-aligned (q even)
    }

    __shared__ float lg[8][16][2];
    lg[tl][e][hf] = s0 + s1;
    __syncthreads();

    if (tid < 8) {
        int tk = blockIdx.x * 8 + tid;
        float v1 = -3.0e38f, v2 = -3.0e38f;
        int i1 = 0, i2 = 0;
        #pragma unroll
        for (int k = 0; k < E; ++k) {
            float v = lg[tid][k][0] + lg[tid][k][1];
            if (v > v1) { v2 = v1; i2 = i1; v1 = v; i1 = k; }
            else if (v > v2) { v2 = v; i2 = k; }
        }
        // renormalized top-2 softmax == softmax over the two winning logits
        float w1 = 1.f / (1.f + expf(v2 - v1));
        float w2 = 1.f - w1;
        int p = atomicAdd(&cnt[i1], 1);
        entries[i1 * T + p] = tk * 2;
        wlist[i1 * T + p] = w1;
        p = atomicAdd(&cnt[i2], 1);
        entries[i2 * T + p] = tk * 2 + 1;
        wlist[i2 * T + p] = w2;
    }
}

// ------------------------------------------------------------------
// Grouped gate/up GEMM + SwiGLU, bf16 MFMA. Tile M=128 x N=64, BK=32.
// ZERO-LDS K-loop: A fragments (xb, L2/L3-resident bf16) and B
// fragments (f32 weights, HBM stream, packed to bf16 in-register)
// load straight into registers. Weight rows had zero intra-block
// reuse (1 wave each) so LDS staging was pure overhead; X's 4x wave
// reuse is served by L1/L2. No __syncthreads in the loop -> no
// vmcnt(0) barrier drain; one-step register rotation + unroll 2
// lets loads stay in flight across iterations.
// ------------------------------------------------------------------
__global__ __launch_bounds__(256, 2) void gateup_mfma(
    const short* __restrict__ xb,      // [T,H] bf16
    const float* __restrict__ gate_p,  // [E,I,H] f32
    const float* __restrict__ up_p,    // [E,I,H] f32
    const int* __restrict__ cnt,
    const int* __restrict__ entries,
    short* __restrict__ hmid)          // [2T,I] bf16, row = slot = t*2+k
{
    int e, t0, n;
    if (!find_item(cnt, blockIdx.x, e, t0, n)) return;
    const int i0 = blockIdx.y * 64;

    __shared__ int toks[128];
    const int tid = threadIdx.x;
    if (tid < 128) {
        int r = t0 + tid;
        toks[tid] = (r < n) ? entries[e * T + r] : -1;
    }
    __syncthreads();   // only barrier in the kernel

    const int lane = tid & 63, wave = tid >> 6;
    const int m16 = lane & 15, q = lane >> 4;

    // A-fragment row bases: lane (m16,q) of frag mi reads 16B at
    // xb[token[mi*16+m16]][k0 + q*8 .. +8]
    const short* abase[8];
    #pragma unroll
    for (int mi = 0; mi < 8; ++mi) {
        int tk = toks[mi * 16 + m16];
        abase[mi] = xb + (size_t)((tk >= 0 ? tk : 0) >> 1) * H + q * 8;
    }
    // B-fragment bases: weight row = output col (i0 + wave*16 + m16),
    // lane reads f32 k-slice [k0 + q*8, +8)
    const size_t wroff = (size_t)e * I * H + (size_t)(i0 + wave * 16 + m16) * H + q * 8;
    const float* gb = gate_p + wroff;
    const float* ub = up_p + wroff;

    f32x4 accg[8], accu[8];
    #pragma unroll
    for (int a = 0; a < 8; ++a) {
        accg[a] = (f32x4){0.f, 0.f, 0.f, 0.f};
        accu[a] = (f32x4){0.f, 0.f, 0.f, 0.f};
    }

    // prologue: chunk 0 in flight
    short8 xc[8];
    #pragma unroll
    for (int mi = 0; mi < 8; ++mi) xc[mi] = *(const short8*)(abase[mi]);
    float4 gc0 = *(const float4*)(gb),     gc1 = *(const float4*)(gb + 4);
    float4 uc0 = *(const float4*)(ub),     uc1 = *(const float4*)(ub + 4);

    #pragma unroll 2
    for (int k0 = 0; k0 < H; k0 += 32) {
        int kn = (k0 + 32 < H) ? k0 + 32 : 0;
        // issue next chunk's loads (in flight during MFMA below)
        short8 xn[8];
        #pragma unroll
        for (int mi = 0; mi < 8; ++mi) xn[mi] = *(const short8*)(abase[mi] + kn);
        float4 gn0 = *(const float4*)(gb + kn), gn1 = *(const float4*)(gb + kn + 4);
        float4 un0 = *(const float4*)(ub + kn), un1 = *(const float4*)(ub + kn + 4);

        short8 bg = pack8(gc0, gc1);
        short8 bu = pack8(uc0, uc1);
        #pragma unroll
        for (int mi = 0; mi < 8; ++mi) {
            accg[mi] = __builtin_amdgcn_mfma_f32_16x16x32_bf16(xc[mi], bg, accg[mi], 0, 0, 0);
            accu[mi] = __builtin_amdgcn_mfma_f32_16x16x32_bf16(xc[mi], bu, accu[mi], 0, 0, 0);
        }
        #pragma unroll
        for (int mi = 0; mi < 8; ++mi) xc[mi] = xn[mi];
        gc0 = gn0; gc1 = gn1; uc0 = un0; uc1 = un1;
    }

    // epilogue: SwiGLU, scalar bf16 stores
    const int col = i0 + wave * 16 + m16;
    #pragma unroll
    for (int mi = 0; mi < 8; ++mi)
        #pragma unroll
        for (int j = 0; j < 4; ++j) {
            int row = mi * 16 + q * 4 + j;
            int slot = toks[row];
            if (slot < 0) continue;
            float g = accg[mi][j];
            float u = accu[mi][j];
            float hv = g / (1.f + expf(-g)) * u;
            ((unsigned short*)hmid)[(size_t)slot * I + col] = (unsigned short)f2bf(hv);
        }
}

// ------------------------------------------------------------------
// Grouped down GEMM, same zero-LDS structure. Tile M=128 x N=64,
// BK=32, 24 K-steps. A = hmid (bf16, L3-resident, gathered rows),
// B = down_p f32 stream. f32 atomic combine (2-way contention).
// ------------------------------------------------------------------
__global__ __launch_bounds__(256, 2) void down_mfma(
    const short* __restrict__ hmid,    // [2T,I] bf16
    const float* __restrict__ down_p,  // [E,H,I] f32
    const int* __restrict__ cnt,
    const int* __restrict__ entries,
    const float* __restrict__ wlist,
    float* __restrict__ out)           // [T,H], pre-zeroed
{
    int e, t0, n;
    if (!find_item(cnt, blockIdx.x, e, t0, n)) return;
    const int h0 = blockIdx.y * 64;

    __shared__ int toks[128];
    __shared__ float wr[128];
    const int tid = threadIdx.x;
    if (tid < 128) {
        int r = t0 + tid;
        bool v = (r < n);
        toks[tid] = v ? entries[e * T + r] : -1;
        wr[tid]   = v ? wlist[e * T + r] : 0.f;
    }
    __syncthreads();   // only barrier in the kernel

    const int lane = tid & 63, wave = tid >> 6;
    const int m16 = lane & 15, q = lane >> 4;

    const short* abase[8];
    #pragma unroll
    for (int mi = 0; mi < 8; ++mi) {
        int slot = toks[mi * 16 + m16];
        abase[mi] = hmid + (size_t)(slot >= 0 ? slot : 0) * I + q * 8;
    }
    const float* bb = down_p + (size_t)e * H * I
                    + (size_t)(h0 + wave * 16 + m16) * I + q * 8;

    f32x4 acc[8];
    #pragma unroll
    for (int a = 0; a < 8; ++a) acc[a] = (f32x4){0.f, 0.f, 0.f, 0.f};

    short8 xc[8];
    #pragma unroll
    for (int mi = 0; mi < 8; ++mi) xc[mi] = *(const short8*)(abase[mi]);
    float4 bc0 = *(const float4*)(bb), bc1 = *(const float4*)(bb + 4);

    #pragma unroll 2
    for (int k0 = 0; k0 < I; k0 += 32) {
        int kn = (k0 + 32 < I) ? k0 + 32 : 0;
        short8 xn[8];
        #pragma unroll
        for (int mi = 0; mi < 8; ++mi) xn[mi] = *(const short8*)(abase[mi] + kn);
        float4 bn0 = *(const float4*)(bb + kn), bn1 = *(const float4*)(bb + kn + 4);

        short8 bf = pack8(bc0, bc1);
        #pragma unroll
        for (int mi = 0; mi < 8; ++mi)
            acc[mi] = __builtin_amdgcn_mfma_f32_16x16x32_bf16(xc[mi], bf, acc[mi], 0, 0, 0);
        #pragma unroll
        for (int mi = 0; mi < 8; ++mi) xc[mi] = xn[mi];
        bc0 = bn0; bc1 = bn1;
    }

    const int col = h0 + wave * 16 + m16;
    #pragma unroll
    for (int mi = 0; mi < 8; ++mi)
        #pragma unroll
        for (int j = 0; j < 4; ++j) {
            int row = mi * 16 + q * 4 + j;
            int slot = toks[row];
            if (slot < 0) continue;
            atomicAdd(&out[(size_t)(slot >> 1) * H + col], wr[row] * acc[mi][j]);
        }
}

extern "C" void kernel_launch(void* const* d_in, const int* in_sizes, int n_in,
                              void* d_out, int out_size, void* d_ws, size_t ws_size,
                              hipStream_t stream) {
    const float* x  = (const float*)d_in[0];   // [1,2048,1024]
    const float* gw = (const float*)d_in[1];   // [16,1024]
    const float* gp = (const float*)d_in[2];   // [16,768,1024]
    const float* up = (const float*)d_in[3];   // [16,768,1024]
    const float* dp = (const float*)d_in[4];   // [16,1024,768]
    float* out = (float*)d_out;

    char* ws = (char*)d_ws;
    int*   cnt     = (int*)ws;                       // 16 ints
    int*   entries = (int*)(ws + 2048);              // E*T ints   (128 KB)
    float* wlist   = (float*)(ws + 2048 + 131072);   // E*T floats (128 KB)
    short* xb      = (short*)(ws + 2048 + 262144);   // T*H bf16   (4 MB)
    short* hmid    = xb + (size_t)T * H;             // 2T*I bf16  (6 MB)

    hipMemsetAsync(ws, 0, 2048, stream);
    hipMemsetAsync(out, 0, (size_t)T * H * sizeof(float), stream);

    router_kernel<<<T / 8, 256, 0, stream>>>(x, gw, xb, cnt, entries, wlist);
    gateup_mfma<<<dim3(WMAX, I / 64), 256, 0, stream>>>(
        xb, gp, up, cnt, entries, hmid);
    down_mfma<<<dim3(WMAX, H / 64), 256, 0, stream>>>(
        hmid, dp, cnt, entries, wlist, out);
}

// Round 4
// 292.961 us; speedup vs baseline: 1.3711x; 1.3711x over previous
//
#include <hip/hip_runtime.h>
#include <hip/hip_bf16.h>
#include <cmath>

// Problem constants (Qwen3 MoE block)
constexpr int T = 2048;   // tokens (B*S)
constexpr int H = 1024;   // hidden
constexpr int I = 768;    // intermediate
constexpr int E = 16;     // experts
constexpr int WMAX = 48;  // max M-tiles at M=128: sum ceil(n_e/128) <= 48

typedef short short8 __attribute__((ext_vector_type(8)));
typedef float f32x4  __attribute__((ext_vector_type(4)));

__device__ __forceinline__ short f2bf(float f) {
    __hip_bfloat16 h = __float2bfloat16(f);   // RNE
    return *reinterpret_cast<short*>(&h);
}

__device__ __forceinline__ short8 pack8(float4 a, float4 b) {
    short8 v = {f2bf(a.x), f2bf(a.y), f2bf(a.z), f2bf(a.w),
                f2bf(b.x), f2bf(b.y), f2bf(b.z), f2bf(b.w)};
    return v;
}

// XOR-swizzled LDS index (units: shorts). Row stride 32 bf16 = 64 B.
// Proven conflict-free (SQ_LDS_BANK_CONFLICT = 0, rounds 0-1).
__device__ __forceinline__ int sw(int r, int kg) {
    return r * 32 + (((kg + (r >> 1)) & 3) << 3);
}

// Uniform prefix scan over cnt[] (replaces a worklist kernel).
__device__ __forceinline__ bool find_item(const int* __restrict__ cnt, int bx,
                                          int& e_o, int& t0_o, int& n_o) {
    int c = 0;
    #pragma unroll
    for (int e = 0; e < E; ++e) {
        int n = cnt[e];
        int m = (n + 127) >> 7;
        if (bx < c + m) { e_o = e; t0_o = (bx - c) << 7; n_o = n; return true; }
        c += m;
    }
    return false;
}

// ------------------------------------------------------------------
// Router (fused x->bf16 conversion): block = 8 tokens x 16 experts
// x 2 H-halves; half-H fp32 dot per thread; the (e,hf) thread owning
// q-slice [hf*128 + e*8, +8) also emits those x values as bf16.
// ------------------------------------------------------------------
__global__ __launch_bounds__(256) void router_kernel(
    const float* __restrict__ x,     // [T,H]
    const float* __restrict__ gw,    // [E,H]
    short* __restrict__ xb,          // [T,H] bf16 out
    int* __restrict__ cnt,           // [E]
    int* __restrict__ entries,       // [E,T]  value = t*2 + k
    float* __restrict__ wlist)       // [E,T]
{
    const int tid = threadIdx.x;
    const int tl = tid & 7;              // token
    const int e  = (tid >> 3) & 15;      // expert
    const int hf = tid >> 7;             // H-half
    const int t  = blockIdx.x * 8 + tl;

    const float4* xr = (const float4*)(x + (size_t)t * H);
    const float4* gr = (const float4*)(gw + (size_t)e * H);
    short* xrow = xb + (size_t)t * H;

    float s0 = 0.f, s1 = 0.f;
    const int qlo = hf * 128, qhi = qlo + 128;
    #pragma unroll 8
    for (int q = qlo; q < qhi; q += 2) {
        float4 a = xr[q],     b = gr[q];
        float4 c = xr[q + 1], d = gr[q + 1];
        s0 += a.x * b.x + a.y * b.y + a.z * b.z + a.w * b.w;
        s1 += c.x * d.x + c.y * d.y + c.z * d.z + c.w * d.w;
        if (((q >> 3) & 15) == e)
            *(short8*)(xrow + q * 4) = pack8(a, c);   // 16B-aligned (q even)
    }

    __shared__ float lg[8][16][2];
    lg[tl][e][hf] = s0 + s1;
    __syncthreads();

    if (tid < 8) {
        int tk = blockIdx.x * 8 + tid;
        float v1 = -3.0e38f, v2 = -3.0e38f;
        int i1 = 0, i2 = 0;
        #pragma unroll
        for (int k = 0; k < E; ++k) {
            float v = lg[tid][k][0] + lg[tid][k][1];
            if (v > v1) { v2 = v1; i2 = i1; v1 = v; i1 = k; }
            else if (v > v2) { v2 = v; i2 = k; }
        }
        // renormalized top-2 softmax == softmax over the two winning logits
        float w1 = 1.f / (1.f + expf(v2 - v1));
        float w2 = 1.f - w1;
        int p = atomicAdd(&cnt[i1], 1);
        entries[i1 * T + p] = tk * 2;
        wlist[i1 * T + p] = w1;
        p = atomicAdd(&cnt[i2], 1);
        entries[i2 * T + p] = tk * 2 + 1;
        wlist[i2 * T + p] = w2;
    }
}

// ------------------------------------------------------------------
// Grouped gate/up GEMM + SwiGLU, bf16 MFMA. Tile M=128 x NI=64
// (gate AND up for 64 i-cols), BK=32. Double-buffered LDS, ONE
// barrier per K-step, write-late staging (T14): per half-step
//   issue loads(k+2) -> MFMA on buf[cur](k) -> ds_write buf[nxt](k+1)
//   -> barrier.
// Load->ds_write distance ~= 2 half-steps (~HBM latency); barrier
// only needs lgkmcnt(0) since staging loads target registers, so
// global loads stay in flight across barriers.
// ------------------------------------------------------------------
__global__ __launch_bounds__(256) void gateup_mfma(
    const short* __restrict__ xb,      // [T,H] bf16
    const float* __restrict__ gate_p,  // [E,I,H] f32
    const float* __restrict__ up_p,    // [E,I,H] f32
    const int* __restrict__ cnt,
    const int* __restrict__ entries,
    short* __restrict__ hmid)          // [2T,I] bf16, row = slot = t*2+k
{
    int e, t0, n;
    if (!find_item(cnt, blockIdx.x, e, t0, n)) return;
    const int i0 = blockIdx.y * 64;

    __shared__ short Xs[2][128 * 32];
    __shared__ short Gs[2][64 * 32];
    __shared__ short Us[2][64 * 32];
    __shared__ int toks[128];

    const int tid = threadIdx.x;
    if (tid < 128) {
        int r = t0 + tid;
        toks[tid] = (r < n) ? entries[e * T + r] : -1;
    }
    __syncthreads();

    const int lane = tid & 63, wave = tid >> 6;
    const int m16 = lane & 15, q = lane >> 4;

    // staging coords: 4 threads per row cover the 4 k-slots of BK=32
    const int sr = tid >> 2, skg = tid & 3;
    const int xt0 = toks[sr], xt1 = toks[64 + sr];
    const short* xsrc0 = xb + (size_t)((xt0 >= 0 ? xt0 : 0) >> 1) * H + skg * 8;
    const short* xsrc1 = xb + (size_t)((xt1 >= 0 ? xt1 : 0) >> 1) * H + skg * 8;
    const float* gsrc = gate_p + (size_t)e * I * H + (size_t)(i0 + sr) * H + skg * 8;
    const float* usrc = up_p   + (size_t)e * I * H + (size_t)(i0 + sr) * H + skg * 8;

    f32x4 accg[8], accu[8];
    #pragma unroll
    for (int a = 0; a < 8; ++a) {
        accg[a] = (f32x4){0.f, 0.f, 0.f, 0.f};
        accu[a] = (f32x4){0.f, 0.f, 0.f, 0.f};
    }

#define GU_LOAD(X0, X1, G0, G1, U0, U1, k)                              \
    X0 = *(const short8*)(xsrc0 + (k));                                 \
    X1 = *(const short8*)(xsrc1 + (k));                                 \
    G0 = *(const float4*)(gsrc + (k)); G1 = *(const float4*)(gsrc + (k) + 4); \
    U0 = *(const float4*)(usrc + (k)); U1 = *(const float4*)(usrc + (k) + 4);

#define GU_STORE(buf, X0, X1, G0, G1, U0, U1)                           \
    *(short8*)&Xs[buf][sw(sr, skg)]      = X0;                          \
    *(short8*)&Xs[buf][sw(64 + sr, skg)] = X1;                          \
    *(short8*)&Gs[buf][sw(sr, skg)] = pack8(G0, G1);                    \
    *(short8*)&Us[buf][sw(sr, skg)] = pack8(U0, U1);

#define GU_COMPUTE(buf) {                                               \
    short8 bg = *(const short8*)&Gs[buf][sw(wave * 16 + m16, q)];       \
    short8 bu = *(const short8*)&Us[buf][sw(wave * 16 + m16, q)];       \
    _Pragma("unroll")                                                   \
    for (int mi = 0; mi < 8; ++mi) {                                    \
        short8 af = *(const short8*)&Xs[buf][sw(mi * 16 + m16, q)];     \
        accg[mi] = __builtin_amdgcn_mfma_f32_16x16x32_bf16(af, bg, accg[mi], 0, 0, 0); \
        accu[mi] = __builtin_amdgcn_mfma_f32_16x16x32_bf16(af, bu, accu[mi], 0, 0, 0); \
    } }

    short8 xA0, xA1, xB0, xB1;
    float4 gA0, gA1, uA0, uA1, gB0, gB1, uB0, uB1;

    // prologue: chunk0 -> buf0; chunk32 -> set B (in flight)
    GU_LOAD(xA0, xA1, gA0, gA1, uA0, uA1, 0)
    GU_STORE(0, xA0, xA1, gA0, gA1, uA0, uA1)
    GU_LOAD(xB0, xB1, gB0, gB1, uB0, uB1, 32)
    __syncthreads();

    for (int k0 = 0; k0 < H; k0 += 64) {
        // half-step 0: compute chunk k0 (buf0); stage chunk k0+32 -> buf1
        int ka = (k0 + 64 < H) ? k0 + 64 : 0;
        GU_LOAD(xA0, xA1, gA0, gA1, uA0, uA1, ka)
        GU_COMPUTE(0)
        GU_STORE(1, xB0, xB1, gB0, gB1, uB0, uB1)
        __syncthreads();
        // half-step 1: compute chunk k0+32 (buf1); stage chunk k0+64 -> buf0
        int kb = (k0 + 96 < H) ? k0 + 96 : 0;
        GU_LOAD(xB0, xB1, gB0, gB1, uB0, uB1, kb)
        GU_COMPUTE(1)
        if (k0 + 64 < H) {
            GU_STORE(0, xA0, xA1, gA0, gA1, uA0, uA1)
        }
        __syncthreads();
    }
#undef GU_LOAD
#undef GU_STORE
#undef GU_COMPUTE

    // epilogue: SwiGLU, scalar bf16 stores
    const int col = i0 + wave * 16 + m16;
    #pragma unroll
    for (int mi = 0; mi < 8; ++mi)
        #pragma unroll
        for (int j = 0; j < 4; ++j) {
            int row = mi * 16 + q * 4 + j;
            int slot = toks[row];
            if (slot < 0) continue;
            float g = accg[mi][j];
            float u = accu[mi][j];
            float hv = g / (1.f + expf(-g)) * u;
            ((unsigned short*)hmid)[(size_t)slot * I + col] = (unsigned short)f2bf(hv);
        }
}

// ------------------------------------------------------------------
// Grouped down GEMM, same single-barrier double-buffered pipeline.
// Tile M=128 x N=64, BK=32 (24 K-steps). f32 atomic combine.
// ------------------------------------------------------------------
__global__ __launch_bounds__(256) void down_mfma(
    const short* __restrict__ hmid,    // [2T,I] bf16
    const float* __restrict__ down_p,  // [E,H,I] f32
    const int* __restrict__ cnt,
    const int* __restrict__ entries,
    const float* __restrict__ wlist,
    float* __restrict__ out)           // [T,H], pre-zeroed
{
    int e, t0, n;
    if (!find_item(cnt, blockIdx.x, e, t0, n)) return;
    const int h0 = blockIdx.y * 64;

    __shared__ short As[2][128 * 32];
    __shared__ short Bs[2][64 * 32];
    __shared__ int toks[128];
    __shared__ float wr[128];

    const int tid = threadIdx.x;
    if (tid < 128) {
        int r = t0 + tid;
        bool v = (r < n);
        toks[tid] = v ? entries[e * T + r] : -1;
        wr[tid]   = v ? wlist[e * T + r] : 0.f;
    }
    __syncthreads();

    const int lane = tid & 63, wave = tid >> 6;
    const int m16 = lane & 15, q = lane >> 4;

    const int sr = tid >> 2, skg = tid & 3;
    const int at0 = toks[sr], at1 = toks[64 + sr];
    const short* asrc0 = hmid + (size_t)(at0 >= 0 ? at0 : 0) * I + skg * 8;
    const short* asrc1 = hmid + (size_t)(at1 >= 0 ? at1 : 0) * I + skg * 8;
    const float* bsrc = down_p + (size_t)e * H * I + (size_t)(h0 + sr) * I + skg * 8;

    f32x4 acc[8];
    #pragma unroll
    for (int a = 0; a < 8; ++a) acc[a] = (f32x4){0.f, 0.f, 0.f, 0.f};

#define DN_LOAD(A0, A1, B0, B1, k)                                      \
    A0 = *(const short8*)(asrc0 + (k));                                 \
    A1 = *(const short8*)(asrc1 + (k));                                 \
    B0 = *(const float4*)(bsrc + (k)); B1 = *(const float4*)(bsrc + (k) + 4);

#define DN_STORE(buf, A0, A1, B0, B1)                                   \
    *(short8*)&As[buf][sw(sr, skg)]      = A0;                          \
    *(short8*)&As[buf][sw(64 + sr, skg)] = A1;                          \
    *(short8*)&Bs[buf][sw(sr, skg)] = pack8(B0, B1);

#define DN_COMPUTE(buf) {                                               \
    short8 bf = *(const short8*)&Bs[buf][sw(wave * 16 + m16, q)];       \
    _Pragma("unroll")                                                   \
    for (int mi = 0; mi < 8; ++mi) {                                    \
        short8 af = *(const short8*)&As[buf][sw(mi * 16 + m16, q)];     \
        acc[mi] = __builtin_amdgcn_mfma_f32_16x16x32_bf16(af, bf, acc[mi], 0, 0, 0); \
    } }

    short8 aA0, aA1, aB0, aB1;
    float4 bA0, bA1, bB0, bB1;

    DN_LOAD(aA0, aA1, bA0, bA1, 0)
    DN_STORE(0, aA0, aA1, bA0, bA1)
    DN_LOAD(aB0, aB1, bB0, bB1, 32)
    __syncthreads();

    for (int k0 = 0; k0 < I; k0 += 64) {
        int ka = (k0 + 64 < I) ? k0 + 64 : 0;
        DN_LOAD(aA0, aA1, bA0, bA1, ka)
        DN_COMPUTE(0)
        DN_STORE(1, aB0, aB1, bB0, bB1)
        __syncthreads();
        int kb = (k0 + 96 < I) ? k0 + 96 : 0;
        DN_LOAD(aB0, aB1, bB0, bB1, kb)
        DN_COMPUTE(1)
        if (k0 + 64 < I) {
            DN_STORE(0, aA0, aA1, bA0, bA1)
        }
        __syncthreads();
    }
#undef DN_LOAD
#undef DN_STORE
#undef DN_COMPUTE

    const int col = h0 + wave * 16 + m16;
    #pragma unroll
    for (int mi = 0; mi < 8; ++mi)
        #pragma unroll
        for (int j = 0; j < 4; ++j) {
            int row = mi * 16 + q * 4 + j;
            int slot = toks[row];
            if (slot < 0) continue;
            atomicAdd(&out[(size_t)(slot >> 1) * H + col], wr[row] * acc[mi][j]);
        }
}

extern "C" void kernel_launch(void* const* d_in, const int* in_sizes, int n_in,
                              void* d_out, int out_size, void* d_ws, size_t ws_size,
                              hipStream_t stream) {
    const float* x  = (const float*)d_in[0];   // [1,2048,1024]
    const float* gw = (const float*)d_in[1];   // [16,1024]
    const float* gp = (const float*)d_in[2];   // [16,768,1024]
    const float* up = (const float*)d_in[3];   // [16,768,1024]
    const float* dp = (const float*)d_in[4];   // [16,1024,768]
    float* out = (float*)d_out;

    char* ws = (char*)d_ws;
    int*   cnt     = (int*)ws;                       // 16 ints
    int*   entries = (int*)(ws + 2048);              // E*T ints   (128 KB)
    float* wlist   = (float*)(ws + 2048 + 131072);   // E*T floats (128 KB)
    short* xb      = (short*)(ws + 2048 + 262144);   // T*H bf16   (4 MB)
    short* hmid    = xb + (size_t)T * H;             // 2T*I bf16  (6 MB)

    hipMemsetAsync(ws, 0, 2048, stream);
    hipMemsetAsync(out, 0, (size_t)T * H * sizeof(float), stream);

    router_kernel<<<T / 8, 256, 0, stream>>>(x, gw, xb, cnt, entries, wlist);
    gateup_mfma<<<dim3(WMAX, I / 64), 256, 0, stream>>>(
        xb, gp, up, cnt, entries, hmid);
    down_mfma<<<dim3(WMAX, H / 64), 256, 0, stream>>>(
        hmid, dp, cnt, entries, wlist, out);
}

// Round 5
// 289.273 us; speedup vs baseline: 1.3886x; 1.0127x over previous
//
#include <hip/hip_runtime.h>
#include <hip/hip_bf16.h>
#include <cmath>

// Problem constants (Qwen3 MoE block)
constexpr int T = 2048;   // tokens (B*S)
constexpr int H = 1024;   // hidden
constexpr int I = 768;    // intermediate
constexpr int E = 16;     // experts
constexpr int WMAX = 48;  // max M-tiles at M=128: sum ceil(n_e/128) <= 47

typedef short short8  __attribute__((ext_vector_type(8)));
typedef short short4v __attribute__((ext_vector_type(4)));
typedef float f32x4   __attribute__((ext_vector_type(4)));

__device__ __forceinline__ short f2bf(float f) {
    __hip_bfloat16 h = __float2bfloat16(f);   // RNE
    return *reinterpret_cast<short*>(&h);
}

__device__ __forceinline__ short8 pack8(float4 a, float4 b) {
    short8 v = {f2bf(a.x), f2bf(a.y), f2bf(a.z), f2bf(a.w),
                f2bf(b.x), f2bf(b.y), f2bf(b.z), f2bf(b.w)};
    return v;
}

// XOR-swizzled LDS index (units: shorts). Row stride 32 bf16 = 64 B.
// Proven conflict-free (SQ_LDS_BANK_CONFLICT = 0, rounds 0-1).
__device__ __forceinline__ int sw(int r, int kg) {
    return r * 32 + (((kg + (r >> 1)) & 3) << 3);
}

// Uniform prefix scan over cnt[] (replaces a worklist kernel).
__device__ __forceinline__ bool find_item(const int* __restrict__ cnt, int bx,
                                          int& e_o, int& t0_o, int& n_o) {
    int c = 0;
    #pragma unroll
    for (int e = 0; e < E; ++e) {
        int n = cnt[e];
        int m = (n + 127) >> 7;
        if (bx < c + m) { e_o = e; t0_o = (bx - c) << 7; n_o = n; return true; }
        c += m;
    }
    return false;
}

// ------------------------------------------------------------------
// Weight transform: fp32 row-major -> bf16 tiles laid out in the
// exact order the GEMM staging consumes. Chunk = [64 rows x 32 k]
// bf16 = 4 KB contiguous; within chunk, pos = ((r*4 + kslot)*8 + j)
// so GEMM thread tid reads short8 at chunk + tid*8 (wave = 1 KB
// contiguous). Linear grid-stride float4 reads = perfectly coalesced
// streaming; writes are 8B each but L2 write-combines (rows fill
// consecutive 64B runs).
// ------------------------------------------------------------------
__global__ __launch_bounds__(256) void cvt_guw(
    const float* __restrict__ gp, const float* __restrict__ up,
    short* __restrict__ wtg, short* __restrict__ wtu)
{
    const int N4 = (E * I * H) / 4;          // 3,145,728 float4 per matrix
    const int stride = gridDim.x * 256;
    #pragma unroll 2
    for (int l4 = blockIdx.x * 256 + threadIdx.x; l4 < 2 * N4; l4 += stride) {
        const bool isu = (l4 >= N4);
        const int l = (isu ? l4 - N4 : l4) << 2;
        const float* src = isu ? up : gp;
        short* dst = isu ? wtu : wtg;
        float4 v = *(const float4*)(src + l);
        int e = l / (I * H);                  // const div -> mul/shift
        int rem = l - e * (I * H);
        int i = rem >> 10, kk = rem & 1023;   // row in [0,768), k in [0,1024)
        int chunk = ((e * 12 + (i >> 6)) * 32 + (kk >> 5)) << 11;
        int pos = chunk + (((i & 63) << 2) + ((kk >> 3) & 3)) * 8 + (kk & 7);
        short4v s = {f2bf(v.x), f2bf(v.y), f2bf(v.z), f2bf(v.w)};
        *(short4v*)(dst + pos) = s;
    }
}

__global__ __launch_bounds__(256) void cvt_dw(
    const float* __restrict__ dp, short* __restrict__ wtd)
{
    const int N4 = (E * H * I) / 4;          // 3,145,728
    const int stride = gridDim.x * 256;
    #pragma unroll 2
    for (int l4 = blockIdx.x * 256 + threadIdx.x; l4 < N4; l4 += stride) {
        const int l = l4 << 2;
        float4 v = *(const float4*)(dp + l);
        int e = l / (H * I);
        int rem = l - e * (H * I);
        int h = rem / 768, kk = rem - h * 768;  // row in [0,1024), k in [0,768)
        int chunk = ((e * 16 + (h >> 6)) * 24 + (kk >> 5)) << 11;
        int pos = chunk + (((h & 63) << 2) + ((kk >> 3) & 3)) * 8 + (kk & 7);
        short4v s = {f2bf(v.x), f2bf(v.y), f2bf(v.z), f2bf(v.w)};
        *(short4v*)(wtd + pos) = s;
    }
}

// ------------------------------------------------------------------
// Router (fused x->bf16 conversion): block = 8 tokens x 16 experts
// x 2 H-halves; half-H fp32 dot per thread; the (e,hf) thread owning
// q-slice [hf*128 + e*8, +8) also emits those x values as bf16.
// ------------------------------------------------------------------
__global__ __launch_bounds__(256) void router_kernel(
    const float* __restrict__ x,     // [T,H]
    const float* __restrict__ gw,    // [E,H]
    short* __restrict__ xb,          // [T,H] bf16 out
    int* __restrict__ cnt,           // [E]
    int* __restrict__ entries,       // [E,T]  value = t*2 + k
    float* __restrict__ wlist)       // [E,T]
{
    const int tid = threadIdx.x;
    const int tl = tid & 7;              // token
    const int e  = (tid >> 3) & 15;      // expert
    const int hf = tid >> 7;             // H-half
    const int t  = blockIdx.x * 8 + tl;

    const float4* xr = (const float4*)(x + (size_t)t * H);
    const float4* gr = (const float4*)(gw + (size_t)e * H);
    short* xrow = xb + (size_t)t * H;

    float s0 = 0.f, s1 = 0.f;
    const int qlo = hf * 128, qhi = qlo + 128;
    #pragma unroll 8
    for (int q = qlo; q < qhi; q += 2) {
        float4 a = xr[q],     b = gr[q];
        float4 c = xr[q + 1], d = gr[q + 1];
        s0 += a.x * b.x + a.y * b.y + a.z * b.z + a.w * b.w;
        s1 += c.x * d.x + c.y * d.y + c.z * d.z + c.w * d.w;
        if (((q >> 3) & 15) == e)
            *(short8*)(xrow + q * 4) = pack8(a, c);   // 16B-aligned (q even)
    }

    __shared__ float lg[8][16][2];
    lg[tl][e][hf] = s0 + s1;
    __syncthreads();

    if (tid < 8) {
        int tk = blockIdx.x * 8 + tid;
        float v1 = -3.0e38f, v2 = -3.0e38f;
        int i1 = 0, i2 = 0;
        #pragma unroll
        for (int k = 0; k < E; ++k) {
            float v = lg[tid][k][0] + lg[tid][k][1];
            if (v > v1) { v2 = v1; i2 = i1; v1 = v; i1 = k; }
            else if (v > v2) { v2 = v; i2 = k; }
        }
        // renormalized top-2 softmax == softmax over the two winning logits
        float w1 = 1.f / (1.f + expf(v2 - v1));
        float w2 = 1.f - w1;
        int p = atomicAdd(&cnt[i1], 1);
        entries[i1 * T + p] = tk * 2;
        wlist[i1 * T + p] = w1;
        p = atomicAdd(&cnt[i2], 1);
        entries[i2 * T + p] = tk * 2 + 1;
        wlist[i2 * T + p] = w2;
    }
}

// ------------------------------------------------------------------
// Grouped gate/up GEMM + SwiGLU, bf16 MFMA. Tile M=128 x NI=64,
// BK=32. R0 structure (best measured): store LDS -> prefetch next ->
// barrier -> MFMA -> barrier. TILED: weights come from the bf16
// tile buffer (1 short8/thread/K-step, contiguous 128 KB stream per
// block). Fallback: fp32 row-major with in-register pack (legacy).
// ------------------------------------------------------------------
template<bool TILED>
__global__ __launch_bounds__(256) void gateup_mfma(
    const short* __restrict__ xb,      // [T,H] bf16
    const float* __restrict__ gate_p,  // [E,I,H] f32
    const float* __restrict__ up_p,    // [E,I,H] f32
    const short* __restrict__ wtg,     // tiled bf16 gate (TILED)
    const short* __restrict__ wtu,     // tiled bf16 up   (TILED)
    const int* __restrict__ cnt,
    const int* __restrict__ entries,
    short* __restrict__ hmid)          // [2T,I] bf16, row = slot = t*2+k
{
    int e, t0, n;
    if (!find_item(cnt, blockIdx.x, e, t0, n)) return;
    const int i0 = blockIdx.y * 64;

    __shared__ short Xs[128 * 32];
    __shared__ short Gs[64 * 32];
    __shared__ short Us[64 * 32];
    __shared__ int toks[128];

    const int tid = threadIdx.x;
    if (tid < 128) {
        int r = t0 + tid;
        toks[tid] = (r < n) ? entries[e * T + r] : -1;
    }
    __syncthreads();

    const int lane = tid & 63, wave = tid >> 6;
    const int m16 = lane & 15, q = lane >> 4;

    // staging coords: 4 threads per row cover the 4 k-slots of BK=32
    const int sr = tid >> 2, skg = tid & 3;
    const int xt0 = toks[sr], xt1 = toks[64 + sr];
    const short* xsrc0 = xb + (size_t)((xt0 >= 0 ? xt0 : 0) >> 1) * H + skg * 8;
    const short* xsrc1 = xb + (size_t)((xt1 >= 0 ? xt1 : 0) >> 1) * H + skg * 8;
    // legacy fp32 sources
    const float* gsrc = gate_p + (size_t)e * I * H + (size_t)(i0 + sr) * H + skg * 8;
    const float* usrc = up_p   + (size_t)e * I * H + (size_t)(i0 + sr) * H + skg * 8;
    // tiled bf16 sources: panel (e, blockIdx.y), chunk stride 2048 shorts
    const short* gts = wtg + ((size_t)(e * 12 + blockIdx.y) * 32) * 2048 + tid * 8;
    const short* uts = wtu + ((size_t)(e * 12 + blockIdx.y) * 32) * 2048 + tid * 8;

    f32x4 accg[8], accu[8];
    #pragma unroll
    for (int a = 0; a < 8; ++a) {
        accg[a] = (f32x4){0.f, 0.f, 0.f, 0.f};
        accu[a] = (f32x4){0.f, 0.f, 0.f, 0.f};
    }

    // prologue: chunk 0
    short8 xc0 = *(const short8*)xsrc0;
    short8 xc1 = *(const short8*)xsrc1;
    short8 gt, ut;
    float4 gc0, gc1, uc0, uc1;
    if constexpr (TILED) {
        gt = *(const short8*)gts;
        ut = *(const short8*)uts;
    } else {
        gc0 = *(const float4*)gsrc; gc1 = *(const float4*)(gsrc + 4);
        uc0 = *(const float4*)usrc; uc1 = *(const float4*)(usrc + 4);
    }

    for (int ks = 0; ks < H / 32; ++ks) {
        // store current chunk to LDS
        *(short8*)&Xs[sw(sr, skg)]      = xc0;
        *(short8*)&Xs[sw(64 + sr, skg)] = xc1;
        if constexpr (TILED) {
            *(short8*)&Gs[sw(sr, skg)] = gt;
            *(short8*)&Us[sw(sr, skg)] = ut;
        } else {
            *(short8*)&Gs[sw(sr, skg)] = pack8(gc0, gc1);
            *(short8*)&Us[sw(sr, skg)] = pack8(uc0, uc1);
        }
        // prefetch next chunk (in flight during MFMA below)
        int ksn = (ks + 1 < H / 32) ? ks + 1 : 0;
        int kn = ksn * 32;
        xc0 = *(const short8*)(xsrc0 + kn);
        xc1 = *(const short8*)(xsrc1 + kn);
        if constexpr (TILED) {
            gt = *(const short8*)(gts + ksn * 2048);
            ut = *(const short8*)(uts + ksn * 2048);
        } else {
            gc0 = *(const float4*)(gsrc + kn); gc1 = *(const float4*)(gsrc + kn + 4);
            uc0 = *(const float4*)(usrc + kn); uc1 = *(const float4*)(usrc + kn + 4);
        }
        __syncthreads();

        short8 bg = *(const short8*)&Gs[sw(wave * 16 + m16, q)];
        short8 bu = *(const short8*)&Us[sw(wave * 16 + m16, q)];
        #pragma unroll
        for (int mi = 0; mi < 8; ++mi) {
            short8 af = *(const short8*)&Xs[sw(mi * 16 + m16, q)];
            accg[mi] = __builtin_amdgcn_mfma_f32_16x16x32_bf16(af, bg, accg[mi], 0, 0, 0);
            accu[mi] = __builtin_amdgcn_mfma_f32_16x16x32_bf16(af, bu, accu[mi], 0, 0, 0);
        }
        __syncthreads();
    }

    // epilogue: SwiGLU, scalar bf16 stores
    const int col = i0 + wave * 16 + m16;
    #pragma unroll
    for (int mi = 0; mi < 8; ++mi)
        #pragma unroll
        for (int j = 0; j < 4; ++j) {
            int row = mi * 16 + q * 4 + j;
            int slot = toks[row];
            if (slot < 0) continue;
            float g = accg[mi][j];
            float u = accu[mi][j];
            float hv = g / (1.f + expf(-g)) * u;
            ((unsigned short*)hmid)[(size_t)slot * I + col] = (unsigned short)f2bf(hv);
        }
}

// ------------------------------------------------------------------
// Grouped down GEMM, same structure. Tile M=128 x N=64, BK=32
// (24 K-steps). f32 atomic combine (2-way contention only).
// ------------------------------------------------------------------
template<bool TILED>
__global__ __launch_bounds__(256) void down_mfma(
    const short* __restrict__ hmid,    // [2T,I] bf16
    const float* __restrict__ down_p,  // [E,H,I] f32
    const short* __restrict__ wtd,     // tiled bf16 down (TILED)
    const int* __restrict__ cnt,
    const int* __restrict__ entries,
    const float* __restrict__ wlist,
    float* __restrict__ out)           // [T,H], pre-zeroed
{
    int e, t0, n;
    if (!find_item(cnt, blockIdx.x, e, t0, n)) return;
    const int h0 = blockIdx.y * 64;

    __shared__ short As[128 * 32];
    __shared__ short Bs[64 * 32];
    __shared__ int toks[128];
    __shared__ float wr[128];

    const int tid = threadIdx.x;
    if (tid < 128) {
        int r = t0 + tid;
        bool v = (r < n);
        toks[tid] = v ? entries[e * T + r] : -1;
        wr[tid]   = v ? wlist[e * T + r] : 0.f;
    }
    __syncthreads();

    const int lane = tid & 63, wave = tid >> 6;
    const int m16 = lane & 15, q = lane >> 4;

    const int sr = tid >> 2, skg = tid & 3;
    const int at0 = toks[sr], at1 = toks[64 + sr];
    const short* asrc0 = hmid + (size_t)(at0 >= 0 ? at0 : 0) * I + skg * 8;
    const short* asrc1 = hmid + (size_t)(at1 >= 0 ? at1 : 0) * I + skg * 8;
    const float* bsrc = down_p + (size_t)e * H * I + (size_t)(h0 + sr) * I + skg * 8;
    const short* bts = wtd + ((size_t)(e * 16 + blockIdx.y) * 24) * 2048 + tid * 8;

    f32x4 acc[8];
    #pragma unroll
    for (int a = 0; a < 8; ++a) acc[a] = (f32x4){0.f, 0.f, 0.f, 0.f};

    short8 ac0 = *(const short8*)asrc0;
    short8 ac1 = *(const short8*)asrc1;
    short8 bt;
    float4 bc0, bc1;
    if constexpr (TILED) {
        bt = *(const short8*)bts;
    } else {
        bc0 = *(const float4*)bsrc; bc1 = *(const float4*)(bsrc + 4);
    }

    for (int ks = 0; ks < I / 32; ++ks) {
        *(short8*)&As[sw(sr, skg)]      = ac0;
        *(short8*)&As[sw(64 + sr, skg)] = ac1;
        if constexpr (TILED) {
            *(short8*)&Bs[sw(sr, skg)] = bt;
        } else {
            *(short8*)&Bs[sw(sr, skg)] = pack8(bc0, bc1);
        }
        int ksn = (ks + 1 < I / 32) ? ks + 1 : 0;
        int kn = ksn * 32;
        ac0 = *(const short8*)(asrc0 + kn);
        ac1 = *(const short8*)(asrc1 + kn);
        if constexpr (TILED) {
            bt = *(const short8*)(bts + ksn * 2048);
        } else {
            bc0 = *(const float4*)(bsrc + kn); bc1 = *(const float4*)(bsrc + kn + 4);
        }
        __syncthreads();

        short8 bf = *(const short8*)&Bs[sw(wave * 16 + m16, q)];
        #pragma unroll
        for (int mi = 0; mi < 8; ++mi) {
            short8 af = *(const short8*)&As[sw(mi * 16 + m16, q)];
            acc[mi] = __builtin_amdgcn_mfma_f32_16x16x32_bf16(af, bf, acc[mi], 0, 0, 0);
        }
        __syncthreads();
    }

    const int col = h0 + wave * 16 + m16;
    #pragma unroll
    for (int mi = 0; mi < 8; ++mi)
        #pragma unroll
        for (int j = 0; j < 4; ++j) {
            int row = mi * 16 + q * 4 + j;
            int slot = toks[row];
            if (slot < 0) continue;
            atomicAdd(&out[(size_t)(slot >> 1) * H + col], wr[row] * acc[mi][j]);
        }
}

extern "C" void kernel_launch(void* const* d_in, const int* in_sizes, int n_in,
                              void* d_out, int out_size, void* d_ws, size_t ws_size,
                              hipStream_t stream) {
    const float* x  = (const float*)d_in[0];   // [1,2048,1024]
    const float* gw = (const float*)d_in[1];   // [16,1024]
    const float* gp = (const float*)d_in[2];   // [16,768,1024]
    const float* up = (const float*)d_in[3];   // [16,768,1024]
    const float* dp = (const float*)d_in[4];   // [16,1024,768]
    float* out = (float*)d_out;

    char* ws = (char*)d_ws;
    int*   cnt     = (int*)ws;                       // 16 ints
    int*   entries = (int*)(ws + 2048);              // E*T ints   (128 KB)
    float* wlist   = (float*)(ws + 2048 + 131072);   // E*T floats (128 KB)
    short* xb      = (short*)(ws + 2048 + 262144);   // T*H bf16   (4 MB)
    short* hmid    = xb + (size_t)T * H;             // 2T*I bf16  (6 MB)
    short* wtg     = hmid + (size_t)2 * T * I;       // 24 MB bf16 tiled gate
    short* wtu     = wtg + (size_t)E * I * H;        // 24 MB bf16 tiled up
    short* wtd     = wtu + (size_t)E * I * H;        // 24 MB bf16 tiled down
    const size_t NEED = 2048 + 262144
                      + (size_t)T * H * 2          // xb
                      + (size_t)2 * T * I * 2      // hmid
                      + (size_t)3 * E * I * H * 2; // wtg+wtu+wtd
    const bool tiled = (ws_size >= NEED);

    hipMemsetAsync(ws, 0, 2048, stream);
    hipMemsetAsync(out, 0, (size_t)T * H * sizeof(float), stream);

    router_kernel<<<T / 8, 256, 0, stream>>>(x, gw, xb, cnt, entries, wlist);
    if (tiled) {
        cvt_guw<<<2048, 256, 0, stream>>>(gp, up, wtg, wtu);
        cvt_dw<<<2048, 256, 0, stream>>>(dp, wtd);
        gateup_mfma<true><<<dim3(WMAX, I / 64), 256, 0, stream>>>(
            xb, gp, up, wtg, wtu, cnt, entries, hmid);
        down_mfma<true><<<dim3(WMAX, H / 64), 256, 0, stream>>>(
            hmid, dp, wtd, cnt, entries, wlist, out);
    } else {
        gateup_mfma<false><<<dim3(WMAX, I / 64), 256, 0, stream>>>(
            xb, gp, up, nullptr, nullptr, cnt, entries, hmid);
        down_mfma<false><<<dim3(WMAX, H / 64), 256, 0, stream>>>(
            hmid, dp, nullptr, cnt, entries, wlist, out);
    }
}

// Round 6
// 285.056 us; speedup vs baseline: 1.4091x; 1.0148x over previous
//
#include <hip/hip_runtime.h>
#include <hip/hip_bf16.h>
#include <cmath>

// Problem constants (Qwen3 MoE block)
constexpr int T = 2048;   // tokens (B*S)
constexpr int H = 1024;   // hidden
constexpr int I = 768;    // intermediate
constexpr int E = 16;     // experts
constexpr int WMAX = 48;  // max M-tiles at M=128: sum ceil(n_e/128) <= 47

// Transform work decomposition: item = (matrix, e, 64-row block, 256-k quarter)
// gate: 16e * 12rb * 4kq = 768 items; up: +768; down: 16e * 16rb * 3kq = 768.
constexpr int CVT_ITEMS = 768 * 3;       // 2304
constexpr int RTR_BLOCKS = T / 8;        // 256
constexpr int CS = 2056;                 // LDS chunk stride (shorts): 2048 + 8 pad

typedef short short8  __attribute__((ext_vector_type(8)));
typedef short short4v __attribute__((ext_vector_type(4)));
typedef float f32x4   __attribute__((ext_vector_type(4)));

__device__ __forceinline__ short f2bf(float f) {
    __hip_bfloat16 h = __float2bfloat16(f);   // RNE
    return *reinterpret_cast<short*>(&h);
}

__device__ __forceinline__ short8 pack8(float4 a, float4 b) {
    short8 v = {f2bf(a.x), f2bf(a.y), f2bf(a.z), f2bf(a.w),
                f2bf(b.x), f2bf(b.y), f2bf(b.z), f2bf(b.w)};
    return v;
}

// XOR-swizzled LDS index (units: shorts). Row stride 32 bf16 = 64 B.
// Proven conflict-free (SQ_LDS_BANK_CONFLICT = 0, rounds 0-1).
__device__ __forceinline__ int sw(int r, int kg) {
    return r * 32 + (((kg + (r >> 1)) & 3) << 3);
}

// Uniform prefix scan over cnt[] (replaces a worklist kernel).
__device__ __forceinline__ bool find_item(const int* __restrict__ cnt, int bx,
                                          int& e_o, int& t0_o, int& n_o) {
    int c = 0;
    #pragma unroll
    for (int e = 0; e < E; ++e) {
        int n = cnt[e];
        int m = (n + 127) >> 7;
        if (bx < c + m) { e_o = e; t0_o = (bx - c) << 7; n_o = n; return true; }
        c += m;
    }
    return false;
}

// ------------------------------------------------------------------
// prep: fused {weight transform | router}.
//
// Transform blocks (bid < CVT_ITEMS): blocked transpose through LDS.
//  phase 1: 64 rows x 256 k fp32, read as 1 KB contiguous runs per
//           wave (4 rows/iter), convert bf16, store to LDS in
//           chunk-major output order (chunk = [64r x 32k] = 4 KB,
//           stride CS=2056 shorts to spread banks).
//  phase 2: stream 8 complete chunks = 32 KB FULLY CONTIGUOUS global
//           write (lane = 16 B, wave = 1 KB/instruction).
// Output layout matches the GEMM staging read exactly:
// chunk + tid*8 == row(tid>>2) * 32 + kslot(tid&3)*8.
//
// Router blocks (bid >= CVT_ITEMS): 8 tokens x 16 experts x 2
// H-halves; fp32 dot; the (e,hf) thread owning q-slice
// [hf*128 + e*8, +8) also emits that x slice as bf16.
// ------------------------------------------------------------------
__global__ __launch_bounds__(256) void prep_kernel(
    const float* __restrict__ x,     // [T,H]
    const float* __restrict__ gw,    // [E,H]
    const float* __restrict__ gp,    // [E,I,H] f32
    const float* __restrict__ up,    // [E,I,H] f32
    const float* __restrict__ dp,    // [E,H,I] f32
    short* __restrict__ xb,          // [T,H] bf16
    short* __restrict__ wtg,         // tiled bf16 gate
    short* __restrict__ wtu,         // tiled bf16 up
    short* __restrict__ wtd,         // tiled bf16 down
    int* __restrict__ cnt,           // [E]
    int* __restrict__ entries,       // [E,T]  value = t*2 + k
    float* __restrict__ wlist)       // [E,T]
{
    __shared__ short lds[8 * CS];    // 32.9 KB (transform path)
    __shared__ float lg[8][16][2];   // router path

    const int tid = threadIdx.x;
    const int bid = blockIdx.x;

    if (bid < CVT_ITEMS) {
        // ---- weight transform item ----
        const float* src; short* dst; int K;
        if (bid < 1536) {
            const int mat = bid >= 768;          // 0=gate, 1=up
            const int id3 = mat ? bid - 768 : bid;
            const int e = id3 / 48, rem = id3 - e * 48;
            const int rb = rem >> 2, kq = rem & 3;
            K = H;
            src = (mat ? up : gp) + (size_t)e * I * H + (size_t)(rb * 64) * H + kq * 256;
            dst = (mat ? wtu : wtg) + ((size_t)(e * 12 + rb) * 32 + kq * 8) * 2048;
        } else {
            const int id3 = bid - 1536;
            const int e = id3 / 48, rem = id3 - e * 48;
            const int rb = rem / 3, kq = rem - rb * 3;
            K = I;
            src = dp + (size_t)e * H * I + (size_t)(rb * 64) * I + kq * 256;
            dst = wtd + ((size_t)(e * 16 + rb) * 24 + kq * 8) * 2048;
        }

        // phase 1: 16 iters x (4 rows x 1 KB contiguous read each wave)
        #pragma unroll
        for (int it = 0; it < 16; ++it) {
            const int r  = it * 4 + (tid >> 6);
            const int kk = (tid & 63) * 4;
            float4 v = *(const float4*)(src + (size_t)r * K + kk);
            short4v s = {f2bf(v.x), f2bf(v.y), f2bf(v.z), f2bf(v.w)};
            *(short4v*)&lds[(kk >> 5) * CS + r * 32 + (kk & 31)] = s;
        }
        __syncthreads();
        // phase 2: 8 chunks x 4 KB, contiguous global writes
        #pragma unroll
        for (int j = 0; j < 8; ++j)
            *(short8*)(dst + j * 2048 + tid * 8) =
                *(const short8*)&lds[j * CS + tid * 8];
        return;
    }

    // ---- router block ----
    const int rb  = bid - CVT_ITEMS;
    const int tl = tid & 7;              // token
    const int e  = (tid >> 3) & 15;      // expert
    const int hf = tid >> 7;             // H-half
    const int t  = rb * 8 + tl;

    const float4* xr = (const float4*)(x + (size_t)t * H);
    const float4* gr = (const float4*)(gw + (size_t)e * H);
    short* xrow = xb + (size_t)t * H;

    float s0 = 0.f, s1 = 0.f;
    const int qlo = hf * 128, qhi = qlo + 128;
    #pragma unroll 8
    for (int q = qlo; q < qhi; q += 2) {
        float4 a = xr[q],     b = gr[q];
        float4 c = xr[q + 1], d = gr[q + 1];
        s0 += a.x * b.x + a.y * b.y + a.z * b.z + a.w * b.w;
        s1 += c.x * d.x + c.y * d.y + c.z * d.z + c.w * d.w;
        if (((q >> 3) & 15) == e)
            *(short8*)(xrow + q * 4) = pack8(a, c);   // 16B-aligned (q even)
    }

    lg[tl][e][hf] = s0 + s1;
    __syncthreads();

    if (tid < 8) {
        int tk = rb * 8 + tid;
        float v1 = -3.0e38f, v2 = -3.0e38f;
        int i1 = 0, i2 = 0;
        #pragma unroll
        for (int k = 0; k < E; ++k) {
            float v = lg[tid][k][0] + lg[tid][k][1];
            if (v > v1) { v2 = v1; i2 = i1; v1 = v; i1 = k; }
            else if (v > v2) { v2 = v; i2 = k; }
        }
        // renormalized top-2 softmax == softmax over the two winning logits
        float w1 = 1.f / (1.f + expf(v2 - v1));
        float w2 = 1.f - w1;
        int p = atomicAdd(&cnt[i1], 1);
        entries[i1 * T + p] = tk * 2;
        wlist[i1 * T + p] = w1;
        p = atomicAdd(&cnt[i2], 1);
        entries[i2 * T + p] = tk * 2 + 1;
        wlist[i2 * T + p] = w2;
    }
}

// ------------------------------------------------------------------
// Grouped gate/up GEMM + SwiGLU, bf16 MFMA. Tile M=128 x NI=64,
// BK=32. R0 structure: store LDS -> prefetch next -> barrier ->
// MFMA -> barrier. Weights from the bf16 tile buffer: 1 short8 per
// thread per K-step, contiguous 128 KB stream per block.
// ------------------------------------------------------------------
__global__ __launch_bounds__(256) void gateup_mfma(
    const short* __restrict__ xb,      // [T,H] bf16
    const short* __restrict__ wtg,     // tiled bf16 gate
    const short* __restrict__ wtu,     // tiled bf16 up
    const int* __restrict__ cnt,
    const int* __restrict__ entries,
    short* __restrict__ hmid)          // [2T,I] bf16, row = slot = t*2+k
{
    int e, t0, n;
    if (!find_item(cnt, blockIdx.x, e, t0, n)) return;
    const int i0 = blockIdx.y * 64;

    __shared__ short Xs[128 * 32];
    __shared__ short Gs[64 * 32];
    __shared__ short Us[64 * 32];
    __shared__ int toks[128];

    const int tid = threadIdx.x;
    if (tid < 128) {
        int r = t0 + tid;
        toks[tid] = (r < n) ? entries[e * T + r] : -1;
    }
    __syncthreads();

    const int lane = tid & 63, wave = tid >> 6;
    const int m16 = lane & 15, q = lane >> 4;

    // staging coords: 4 threads per row cover the 4 k-slots of BK=32
    const int sr = tid >> 2, skg = tid & 3;
    const int xt0 = toks[sr], xt1 = toks[64 + sr];
    const short* xsrc0 = xb + (size_t)((xt0 >= 0 ? xt0 : 0) >> 1) * H + skg * 8;
    const short* xsrc1 = xb + (size_t)((xt1 >= 0 ? xt1 : 0) >> 1) * H + skg * 8;
    const short* gts = wtg + ((size_t)(e * 12 + blockIdx.y) * 32) * 2048 + tid * 8;
    const short* uts = wtu + ((size_t)(e * 12 + blockIdx.y) * 32) * 2048 + tid * 8;

    f32x4 accg[8], accu[8];
    #pragma unroll
    for (int a = 0; a < 8; ++a) {
        accg[a] = (f32x4){0.f, 0.f, 0.f, 0.f};
        accu[a] = (f32x4){0.f, 0.f, 0.f, 0.f};
    }

    short8 xc0 = *(const short8*)xsrc0;
    short8 xc1 = *(const short8*)xsrc1;
    short8 gt = *(const short8*)gts;
    short8 ut = *(const short8*)uts;

    for (int ks = 0; ks < H / 32; ++ks) {
        *(short8*)&Xs[sw(sr, skg)]      = xc0;
        *(short8*)&Xs[sw(64 + sr, skg)] = xc1;
        *(short8*)&Gs[sw(sr, skg)] = gt;
        *(short8*)&Us[sw(sr, skg)] = ut;
        int ksn = (ks + 1 < H / 32) ? ks + 1 : 0;
        int kn = ksn * 32;
        xc0 = *(const short8*)(xsrc0 + kn);
        xc1 = *(const short8*)(xsrc1 + kn);
        gt = *(const short8*)(gts + ksn * 2048);
        ut = *(const short8*)(uts + ksn * 2048);
        __syncthreads();

        short8 bg = *(const short8*)&Gs[sw(wave * 16 + m16, q)];
        short8 bu = *(const short8*)&Us[sw(wave * 16 + m16, q)];
        #pragma unroll
        for (int mi = 0; mi < 8; ++mi) {
            short8 af = *(const short8*)&Xs[sw(mi * 16 + m16, q)];
            accg[mi] = __builtin_amdgcn_mfma_f32_16x16x32_bf16(af, bg, accg[mi], 0, 0, 0);
            accu[mi] = __builtin_amdgcn_mfma_f32_16x16x32_bf16(af, bu, accu[mi], 0, 0, 0);
        }
        __syncthreads();
    }

    // epilogue: SwiGLU, scalar bf16 stores
    const int col = i0 + wave * 16 + m16;
    #pragma unroll
    for (int mi = 0; mi < 8; ++mi)
        #pragma unroll
        for (int j = 0; j < 4; ++j) {
            int row = mi * 16 + q * 4 + j;
            int slot = toks[row];
            if (slot < 0) continue;
            float g = accg[mi][j];
            float u = accu[mi][j];
            float hv = g / (1.f + expf(-g)) * u;
            ((unsigned short*)hmid)[(size_t)slot * I + col] = (unsigned short)f2bf(hv);
        }
}

// ------------------------------------------------------------------
// Grouped down GEMM, same structure. Tile M=128 x N=64, BK=32
// (24 K-steps). f32 atomic combine (2-way contention only).
// ------------------------------------------------------------------
__global__ __launch_bounds__(256) void down_mfma(
    const short* __restrict__ hmid,    // [2T,I] bf16
    const short* __restrict__ wtd,     // tiled bf16 down
    const int* __restrict__ cnt,
    const int* __restrict__ entries,
    const float* __restrict__ wlist,
    float* __restrict__ out)           // [T,H], pre-zeroed
{
    int e, t0, n;
    if (!find_item(cnt, blockIdx.x, e, t0, n)) return;
    const int h0 = blockIdx.y * 64;

    __shared__ short As[128 * 32];
    __shared__ short Bs[64 * 32];
    __shared__ int toks[128];
    __shared__ float wr[128];

    const int tid = threadIdx.x;
    if (tid < 128) {
        int r = t0 + tid;
        bool v = (r < n);
        toks[tid] = v ? entries[e * T + r] : -1;
        wr[tid]   = v ? wlist[e * T + r] : 0.f;
    }
    __syncthreads();

    const int lane = tid & 63, wave = tid >> 6;
    const int m16 = lane & 15, q = lane >> 4;

    const int sr = tid >> 2, skg = tid & 3;
    const int at0 = toks[sr], at1 = toks[64 + sr];
    const short* asrc0 = hmid + (size_t)(at0 >= 0 ? at0 : 0) * I + skg * 8;
    const short* asrc1 = hmid + (size_t)(at1 >= 0 ? at1 : 0) * I + skg * 8;
    const short* bts = wtd + ((size_t)(e * 16 + blockIdx.y) * 24) * 2048 + tid * 8;

    f32x4 acc[8];
    #pragma unroll
    for (int a = 0; a < 8; ++a) acc[a] = (f32x4){0.f, 0.f, 0.f, 0.f};

    short8 ac0 = *(const short8*)asrc0;
    short8 ac1 = *(const short8*)asrc1;
    short8 bt = *(const short8*)bts;

    for (int ks = 0; ks < I / 32; ++ks) {
        *(short8*)&As[sw(sr, skg)]      = ac0;
        *(short8*)&As[sw(64 + sr, skg)] = ac1;
        *(short8*)&Bs[sw(sr, skg)]      = bt;
        int ksn = (ks + 1 < I / 32) ? ks + 1 : 0;
        int kn = ksn * 32;
        ac0 = *(const short8*)(asrc0 + kn);
        ac1 = *(const short8*)(asrc1 + kn);
        bt = *(const short8*)(bts + ksn * 2048);
        __syncthreads();

        short8 bf = *(const short8*)&Bs[sw(wave * 16 + m16, q)];
        #pragma unroll
        for (int mi = 0; mi < 8; ++mi) {
            short8 af = *(const short8*)&As[sw(mi * 16 + m16, q)];
            acc[mi] = __builtin_amdgcn_mfma_f32_16x16x32_bf16(af, bf, acc[mi], 0, 0, 0);
        }
        __syncthreads();
    }

    const int col = h0 + wave * 16 + m16;
    #pragma unroll
    for (int mi = 0; mi < 8; ++mi)
        #pragma unroll
        for (int j = 0; j < 4; ++j) {
            int row = mi * 16 + q * 4 + j;
            int slot = toks[row];
            if (slot < 0) continue;
            atomicAdd(&out[(size_t)(slot >> 1) * H + col], wr[row] * acc[mi][j]);
        }
}

extern "C" void kernel_launch(void* const* d_in, const int* in_sizes, int n_in,
                              void* d_out, int out_size, void* d_ws, size_t ws_size,
                              hipStream_t stream) {
    const float* x  = (const float*)d_in[0];   // [1,2048,1024]
    const float* gw = (const float*)d_in[1];   // [16,1024]
    const float* gp = (const float*)d_in[2];   // [16,768,1024]
    const float* up = (const float*)d_in[3];   // [16,768,1024]
    const float* dp = (const float*)d_in[4];   // [16,1024,768]
    float* out = (float*)d_out;

    char* ws = (char*)d_ws;
    int*   cnt     = (int*)ws;                       // 16 ints
    int*   entries = (int*)(ws + 2048);              // E*T ints   (128 KB)
    float* wlist   = (float*)(ws + 2048 + 131072);   // E*T floats (128 KB)
    short* xb      = (short*)(ws + 2048 + 262144);   // T*H bf16   (4 MB)
    short* hmid    = xb + (size_t)T * H;             // 2T*I bf16  (6 MB)
    short* wtg     = hmid + (size_t)2 * T * I;       // 24 MB bf16 tiled gate
    short* wtu     = wtg + (size_t)E * I * H;        // 24 MB bf16 tiled up
    short* wtd     = wtu + (size_t)E * I * H;        // 24 MB bf16 tiled down
    // ws_size >= ~86.3 MB proven on this harness (round 5 ran tiled path).

    hipMemsetAsync(ws, 0, 2048, stream);
    hipMemsetAsync(out, 0, (size_t)T * H * sizeof(float), stream);

    prep_kernel<<<CVT_ITEMS + RTR_BLOCKS, 256, 0, stream>>>(
        x, gw, gp, up, dp, xb, wtg, wtu, wtd, cnt, entries, wlist);
    gateup_mfma<<<dim3(WMAX, I / 64), 256, 0, stream>>>(
        xb, wtg, wtu, cnt, entries, hmid);
    down_mfma<<<dim3(WMAX, H / 64), 256, 0, stream>>>(
        hmid, wtd, cnt, entries, wlist, out);
}